// Round 7
// baseline (1176.322 us; speedup 1.0000x reference)
//
#include <hip/hip_runtime.h>
#include <hip/hip_cooperative_groups.h>
#include <math.h>

namespace cg = cooperative_groups;

#define Dk 1024
#define Ck 32
#define Nk 1024
#define Qk 1024
#define REGP 0.5f
#define NB 64
#define NT (Dk/NB)
#define NROWSV (Qk + Nk + Ck + 1)   // 2081 rows: queries, support (original order), mus, m

// consts layout (floats)
#define CO_KAPPA 0
#define CO_NU    1
#define CO_NJ    2
#define CO_KN    34
#define CO_SCALE 66
#define CO_COMMON 98
#define CO_COEF  130
#define CO_BIASA 162
#define CO_TOTAL 256

// workspace offsets (floats)
#define O_Y    ((size_t)0)
#define O_YO   (O_Y + 2112u*1024u)
#define O_W    (O_YO + 2112u*1024u)
#define O_T    (O_W + 1024u*1024u)
#define O_P    (O_T + 512u*512u)
#define O_MU   (O_P + 1088u*1024u)
#define O_QM   (O_MU + 32u*1024u)
#define O_MB   (O_QM + 32u*1024u)
#define O_QNY  (O_MB + 32u*1224u)
#define O_QNO  (O_QNY + 1024u)
#define O_MUN  (O_QNO + 1024u)
#define O_EX   (O_MUN + 32u)
#define O_CONS (O_EX + 16u)
#define O_CIDX (O_CONS + 256u)

__device__ __forceinline__ float wave_red(float s) {
#pragma unroll
    for (int o = 32; o > 0; o >>= 1) s += __shfl_down(s, o, 64);
    return s;
}

// thread owns a 4x4 sub-tile: rows rg*4..+3, cols c4*4..+3
__device__ __forceinline__ void fetch4(float4* reg, const float* src, int ld,
                                       int rowbase, int rowmax, int colbase, int t) {
    int rg = t >> 4, c4 = t & 15;
#pragma unroll
    for (int u = 0; u < 4; ++u) {
        int gr = rowbase + rg * 4 + u;
        reg[u] = (gr < rowmax) ? *(const float4*)(src + (size_t)gr * ld + colbase + c4 * 4)
                               : make_float4(0.f, 0.f, 0.f, 0.f);
    }
}
// transposed store via in-register 4x4 transpose: dst[k*68 + r], float4 writes (8-way max)
__device__ __forceinline__ void stT(float* dst, const float4* reg, int t) {
    int rg = t >> 4, c4 = t & 15;
    float4 v0 = make_float4(reg[0].x, reg[1].x, reg[2].x, reg[3].x);
    float4 v1 = make_float4(reg[0].y, reg[1].y, reg[2].y, reg[3].y);
    float4 v2 = make_float4(reg[0].z, reg[1].z, reg[2].z, reg[3].z);
    float4 v3 = make_float4(reg[0].w, reg[1].w, reg[2].w, reg[3].w);
    *(float4*)(dst + (c4 * 4 + 0) * 68 + rg * 4) = v0;
    *(float4*)(dst + (c4 * 4 + 1) * 68 + rg * 4) = v1;
    *(float4*)(dst + (c4 * 4 + 2) * 68 + rg * 4) = v2;
    *(float4*)(dst + (c4 * 4 + 3) * 68 + rg * 4) = v3;
}
// straight store: dst[r*68 + c]
__device__ __forceinline__ void stN(float* dst, const float4* reg, int t) {
    int rg = t >> 4, c4 = t & 15;
#pragma unroll
    for (int u = 0; u < 4; ++u)
        *(float4*)(dst + (rg * 4 + u) * 68 + c4 * 4) = reg[u];
}

// acc[r][s] += sum_k At[k][ty*4+r] * Bt[k][tx*4+s]
__device__ __forceinline__ void gemm16(const float* At, const float* Bt,
                                       float acc[4][4], int tx, int ty) {
#pragma unroll 4
    for (int kk = 0; kk < NB; ++kk) {
        float4 a = *(const float4*)(At + kk * 68 + ty * 4);
        float4 b = *(const float4*)(Bt + kk * 68 + tx * 4);
        float av[4] = {a.x, a.y, a.z, a.w};
        float bv[4] = {b.x, b.y, b.z, b.w};
#pragma unroll
        for (int r = 0; r < 4; ++r)
#pragma unroll
            for (int s = 0; s < 4; ++s) acc[r][s] += av[r] * bv[s];
    }
}

// double-buffered-in-registers k-loop tile GEMM
__device__ __forceinline__ void mm_task(
    const float* aSrc, int aLd, int aRow, int aRowMax, int aCol, int aRowStep, int aColStep,
    const float* bSrc, int bLd, int bRow, int bRowMax, int bCol, int bRowStep, int bColStep,
    bool bTrans, int k0, int k1,
    float acc[4][4], float* smA, float* smB, int t, int tx, int ty)
{
    float4 ra[4], rb[4];
    fetch4(ra, aSrc, aLd, aRow + k0 * aRowStep, aRowMax, aCol + k0 * aColStep, t);
    fetch4(rb, bSrc, bLd, bRow + k0 * bRowStep, bRowMax, bCol + k0 * bColStep, t);
    stT(smA, ra, t);
    if (bTrans) stT(smB, rb, t); else stN(smB, rb, t);
    __syncthreads();
    for (int kt = k0; kt < k1; ++kt) {
        if (kt + 1 < k1) {
            fetch4(ra, aSrc, aLd, aRow + (kt + 1) * aRowStep, aRowMax, aCol + (kt + 1) * aColStep, t);
            fetch4(rb, bSrc, bLd, bRow + (kt + 1) * bRowStep, bRowMax, bCol + (kt + 1) * bColStep, t);
        }
        gemm16(smA, smB, acc, tx, ty);
        __syncthreads();
        if (kt + 1 < k1) {
            stT(smA, ra, t);
            if (bTrans) stT(smB, rb, t); else stN(smB, rb, t);
        }
        __syncthreads();
    }
}

__global__ __launch_bounds__(256, 4) void k_all(const float* sx, const float* qx,
                                                const int* labels, const float* mvec,
                                                const float* kappa, const float* nu,
                                                const float* td, const float* tl,
                                                float* Wbuf, float* out) {
    cg::grid_group grid = cg::this_grid();
    __shared__ __align__(16) float smem[8832];
    float* smA = smem;            // 4352
    float* smB = smem + 4352;     // 4352
    float* sX  = smem + 8704;     // 128

    float* Y     = Wbuf + O_Y;
    float* Yo    = Wbuf + O_YO;
    float* W     = Wbuf + O_W;
    float* Tb    = Wbuf + O_T;
    float* P     = Wbuf + O_P;
    float* mu    = Wbuf + O_MU;
    float* QM    = Wbuf + O_QM;
    float* Mbuf  = Wbuf + O_MB;
    float* qny   = Wbuf + O_QNY;
    float* qno   = Wbuf + O_QNO;
    float* mun2o = Wbuf + O_MUN;
    float* extraf= Wbuf + O_EX;
    float* cons  = Wbuf + O_CONS;
    int*   cidx  = (int*)(Wbuf + O_CIDX);

    const int b = blockIdx.x, G = gridDim.x;
    const int t = threadIdx.x;
    const int tx = t & 15, ty = t >> 4;
    const int lane = t & 63, wv = t >> 6;
    const int BIG = 1 << 30;

    // ========== P0: stats, logdet, diag-inv, zeros, qno, copies (no cidx deps) ==========
    for (int tau = b; tau < 417; tau += G) {
        if (tau == 0) {
            int* scnt = (int*)sX;
            if (t < Ck) scnt[t] = 0;
            __syncthreads();
            for (int n = t; n < Nk; n += 256) {
                int l = labels[n];
                int pos = atomicAdd(&scnt[l], 1);
                cidx[l * Nk + pos] = n;
            }
            __syncthreads();
            if (t < Ck) {
                float kap = fabsf(kappa[0]) + 1e-6f;
                float nu_ = fmaxf(nu[0], (float)(Dk - 1) + 1e-6f);
                float Njf = (float)scnt[t];
                float kN = kap + Njf;
                if (t == 0) { cons[CO_KAPPA] = kap; cons[CO_NU] = nu_; }
                cons[CO_NJ + t] = Njf;
                cons[CO_KN + t] = kN;
                cons[CO_SCALE + t] = (kN + 1.0f) / ((nu_ + Njf - (float)Dk + 1.0f) * kN);
                float common = nu_ + Njf + 1.0f - (float)Dk;
                cons[CO_COMMON + t] = common;
                cons[CO_COEF + t] = 0.5f * (common + (float)Dk);
                cons[CO_BIASA + t] = lgammaf(0.5f * (common + (float)Dk)) - lgammaf(0.5f * common)
                                     - 0.5f * (float)Dk * logf(common);
            }
            __syncthreads();
        } else if (tau == 1) {
            float s = 0.f;
            for (int i = t; i < Dk; i += 256) s += logf(fabsf(td[i]));
            s = wave_red(s);
            if (lane == 0) sX[wv] = s;
            __syncthreads();
            if (t == 0) extraf[0] = 2.f * (sX[0] + sX[1] + sX[2] + sX[3]);
            __syncthreads();
        } else if (tau < 18) {
            int I = tau - 2, b0 = I * NB;
            for (int idx = t; idx < NB * NB; idx += 256) {
                int r = idx >> 6, c = idx & 63;
                float v;
                if (c < r) v = tl[(size_t)(b0 + r) * Dk + b0 + c];
                else if (c == r) v = fabsf(td[b0 + r]);
                else v = 0.f;
                smA[r * 68 + c] = v;
            }
            __syncthreads();
            if (t < NB) {
                int j = t;
                smB[j * 68 + j] = 1.f / smA[j * 68 + j];
                for (int i = j + 1; i < NB; ++i) {
                    float s = 0.f;
                    for (int k = j; k < i; ++k) s += smA[i * 68 + k] * smB[k * 68 + j];
                    smB[i * 68 + j] = -s / smA[i * 68 + i];
                }
            }
            __syncthreads();
            for (int idx = t; idx < NB * NB; idx += 256) {
                int r = idx >> 6, c = idx & 63;
                W[(size_t)(b0 + r) * Dk + b0 + c] = (c <= r) ? smB[r * 68 + c] : 0.f;
            }
            __syncthreads();
        } else if (tau < 150) {        // zero Yo
            int rbase = (tau - 18) * 16;
            for (int j = 0; j < 16; ++j)
                ((float4*)(Yo + (size_t)(rbase + j) * Dk))[t] = make_float4(0, 0, 0, 0);
        } else if (tau < 218) {        // zero P
            int rbase = (tau - 150) * 16;
            for (int j = 0; j < 16; ++j)
                ((float4*)(P + (size_t)(rbase + j) * Qk))[t] = make_float4(0, 0, 0, 0);
        } else if (tau < 220) {        // zero QM
            int base = (tau - 218) * 16384;
#pragma unroll
            for (int j = 0; j < 4; ++j)
                ((float4*)(QM + base + j * 4096))[t] = make_float4(0, 0, 0, 0);
        } else if (tau < 223) {        // zero Mbuf (39168)
            int base = (tau - 220) * 13056;
            for (int i = t; i < 13056; i += 256) Mbuf[base + i] = 0.f;
        } else if (tau == 223) {       // zero mun2o
            if (t < 32) mun2o[t] = 0.f;
        } else if (tau < 288) {        // qno
            int rbase = (tau - 224) * 16;
            for (int j = wv; j < 16; j += 4) {
                const float* row = qx + (size_t)(rbase + j) * Dk;
                float s = 0.f;
                for (int d = lane; d < Dk; d += 64) { float v = row[d]; s += v * v; }
                s = wave_red(s);
                if (lane == 0) qno[rbase + j] = s;
            }
        } else if (tau < 352) {        // copy queries into Y
            int rbase = (tau - 288) * 16;
            for (int j = 0; j < 16; ++j) {
                int r = rbase + j;
                ((float4*)(Y + (size_t)r * Dk))[t] = ((const float4*)(qx + (size_t)r * Dk))[t];
            }
        } else if (tau < 416) {        // copy support (original order) into Y
            int rbase = (tau - 352) * 16;
            for (int j = 0; j < 16; ++j) {
                int n = rbase + j;
                ((float4*)(Y + (size_t)(Qk + n) * Dk))[t] = ((const float4*)(sx + (size_t)n * Dk))[t];
            }
        } else {                       // m row
            ((float4*)(Y + (size_t)(Qk + Nk + Ck) * Dk))[t] = ((const float4*)mvec)[t];
        }
    }
    grid.sync();

    // ========== P1: mu (+Y mu-row +mun2o) ==========
    for (int tau = b; tau < 128; tau += G) {
        int c = tau >> 2;
        int d = ((tau & 3) << 8) + t;
        int Nj = (int)cons[CO_NJ + c];
        float kap = cons[CO_KAPPA], kN = cons[CO_KN + c];
        float acc = 0.f;
        for (int s = 0; s < Nj; ++s) acc += sx[(size_t)cidx[c * Nk + s] * Dk + d];
        float muv = (kap * mvec[d] + acc) / kN;
        mu[c * Dk + d] = muv;
        Y[(size_t)(Qk + Nk + c) * Dk + d] = muv;
        float s2 = wave_red(muv * muv);
        if (lane == 0) sX[wv] = s2;
        __syncthreads();
        if (t == 0) atomicAdd(&mun2o[c], sX[0] + sX[1] + sX[2] + sX[3]);
        __syncthreads();
    }
    grid.sync();

    // ========== T1: trtri level-1 (merged) + QM split-K ==========
    for (int tau = b; tau < 72; tau += G) {
        if (tau < 8) {
            int pb = tau * 128;
            float acc[4][4] = {};
            mm_task(tl, Dk, pb + 64, BIG, pb, 0, NB,
                    W, Dk, pb, BIG, pb, NB, 0, false, 0, 1,
                    acc, smA, smB, t, tx, ty);
            {
                float4 ra[4];
                fetch4(ra, W, Dk, pb + 64, BIG, pb + 64, t);
#pragma unroll
                for (int r = 0; r < 4; ++r)
#pragma unroll
                    for (int s = 0; s < 4; ++s)
                        smB[(ty * 4 + r) * 68 + tx * 4 + s] = acc[r][s];
                stT(smA, ra, t);
            }
            __syncthreads();
            float acc2[4][4] = {};
            gemm16(smA, smB, acc2, tx, ty);
            __syncthreads();
#pragma unroll
            for (int r = 0; r < 4; ++r)
#pragma unroll
                for (int s = 0; s < 4; ++s)
                    W[(size_t)(pb + 64 + ty * 4 + r) * Dk + pb + tx * 4 + s] = -acc2[r][s];
        } else {
            int e = tau - 8;
            int qt = e >> 2, kc = e & 3;
            float acc[4][4] = {};
            mm_task(mu, Dk, 0, Ck, 0, 0, NB,
                    qx, Dk, qt * NB, Qk, 0, 0, NB, true, kc * 4, kc * 4 + 4,
                    acc, smA, smB, t, tx, ty);
#pragma unroll
            for (int r = 0; r < 4; ++r) {
                int c = ty * 4 + r;
                if (c < Ck)
#pragma unroll
                    for (int s = 0; s < 4; ++s)
                        atomicAdd(&QM[(size_t)c * Qk + qt * NB + tx * 4 + s], acc[r][s]);
            }
        }
    }
    grid.sync();

    // ========== trtri levels 2..4 ==========
    for (int l = 2; l <= 4; ++l) {
        int h = 32 << l;
        int ht = h >> 6;
        int pairs = 16 >> l;
        int ntask = pairs * ht * ht;
        for (int tau = b; tau < ntask; tau += G) {     // phase A: T = B * Ainv
            int p = tau / (ht * ht), rr = tau % (ht * ht);
            int i = rr / ht, j = rr % ht;
            int pb = p * 2 * h;
            float acc[4][4] = {};
            mm_task(tl, Dk, pb + h + i * NB, BIG, pb, 0, NB,
                    W, Dk, pb, BIG, pb + j * NB, NB, 0, false, 0, ht,
                    acc, smA, smB, t, tx, ty);
            float* Tp = Tb + (size_t)p * h * h;
#pragma unroll
            for (int r = 0; r < 4; ++r)
#pragma unroll
                for (int s = 0; s < 4; ++s)
                    Tp[(size_t)(i * NB + ty * 4 + r) * h + j * NB + tx * 4 + s] = acc[r][s];
        }
        grid.sync();
        for (int tau = b; tau < ntask; tau += G) {     // phase B: W_off = -Cinv * T
            int p = tau / (ht * ht), rr = tau % (ht * ht);
            int i = rr / ht, j = rr % ht;
            int pb = p * 2 * h;
            const float* Tp = Tb + (size_t)p * h * h;
            float acc[4][4] = {};
            mm_task(W, Dk, pb + h + i * NB, BIG, pb + h, 0, NB,
                    Tp, h, 0, BIG, j * NB, NB, 0, false, 0, ht,
                    acc, smA, smB, t, tx, ty);
#pragma unroll
            for (int r = 0; r < 4; ++r)
#pragma unroll
                for (int s = 0; s < 4; ++s)
                    W[(size_t)(pb + h + i * NB + ty * 4 + r) * Dk + pb + j * NB + tx * 4 + s] = -acc[r][s];
        }
        grid.sync();
    }

    // ========== Ygemm split-K: Yo += Y * W^T ==========
    for (int e = b; e < 33 * 40; e += G) {
        int rt = e / 40, w = e - rt * 40;
        int jt, kc;
        if (w < 4) { jt = w; kc = 0; }
        else if (w < 12) { jt = 4 + ((w - 4) >> 1); kc = (w - 4) & 1; }
        else if (w < 24) { jt = 8 + (w - 12) / 3; kc = (w - 12) % 3; }
        else { jt = 12 + ((w - 24) >> 2); kc = (w - 24) & 3; }
        int k0 = kc * 4, k1 = min(jt + 1, k0 + 4);
        float acc[4][4] = {};
        mm_task(Y, Dk, rt * NB, NROWSV, 0, 0, NB,
                W, Dk, jt * NB, BIG, 0, 0, NB, true, k0, k1,
                acc, smA, smB, t, tx, ty);
#pragma unroll
        for (int r = 0; r < 4; ++r) {
            int gr = rt * NB + ty * 4 + r;
            if (gr < NROWSV)
#pragma unroll
                for (int s = 0; s < 4; ++s)
                    atomicAdd(&Yo[(size_t)gr * Dk + jt * NB + tx * 4 + s], acc[r][s]);
        }
    }
    grid.sync();

    // ========== P4: P split-K (1088), gram split-K (128), qny (64) ==========
    for (int tau = b; tau < 1280; tau += G) {
        if (tau < 1088) {
            int kc = tau & 3, qt = (tau >> 2) & 15, nt = tau >> 6;
            float acc[4][4] = {};
            mm_task(Yo + (size_t)Qk * Dk, Dk, nt * NB, Nk + Ck + 1, 0, 0, NB,
                    Yo, Dk, qt * NB, Qk, 0, 0, NB, true, kc * 4, kc * 4 + 4,
                    acc, smA, smB, t, tx, ty);
#pragma unroll
            for (int r = 0; r < 4; ++r) {
                int n = nt * NB + ty * 4 + r;
                if (n < Nk + Ck + 1)
#pragma unroll
                    for (int s = 0; s < 4; ++s)
                        atomicAdd(&P[(size_t)n * Qk + qt * NB + tx * 4 + s], acc[r][s]);
            }
        } else if (tau < 1216) {
            int g = tau - 1088;
            int c = g >> 2, kc = g & 3;
            int* sidx = (int*)sX;
            if (t < 32) sidx[t] = cidx[c * Nk + t];
            __syncthreads();
            float accg[5];
            int iu[5], ju[5];
#pragma unroll
            for (int u = 0; u < 5; ++u) {
                int e = t + u * 256;
                iu[u] = e / 34; ju[u] = e - iu[u] * 34;
                accg[u] = 0.f;
            }
            for (int kt = kc * 4; kt < kc * 4 + 4; ++kt) {
                for (int e2 = t; e2 < 34 * NB; e2 += 256) {
                    int i = e2 >> 6, k = e2 & 63;
                    int yr = (i < 32) ? (Qk + sidx[i]) : ((i == 32) ? (Qk + Nk + c) : (Qk + Nk + Ck));
                    smA[i * 68 + k] = Yo[(size_t)yr * Dk + kt * NB + k];
                }
                __syncthreads();
#pragma unroll
                for (int u = 0; u < 5; ++u) {
                    int e = t + u * 256;
                    if (e < 1156) {
                        float s = 0.f;
                        for (int k = 0; k < NB; ++k) s += smA[iu[u] * 68 + k] * smA[ju[u] * 68 + k];
                        accg[u] += s;
                    }
                }
                __syncthreads();
            }
#pragma unroll
            for (int u = 0; u < 5; ++u) {
                int e = t + u * 256;
                if (e < 1156)
                    atomicAdd(&Mbuf[c * 1224 + iu[u] * 36 + ju[u]], accg[u]);
            }
            __syncthreads();
        } else {
            int rbase = (tau - 1216) * 16;
            for (int j = wv; j < 16; j += 4) {
                const float* row = Yo + (size_t)(rbase + j) * Dk;
                float s = 0.f;
                for (int d = lane; d < Dk; d += 64) { float v = row[d]; s += v * v; }
                s = wave_red(s);
                if (lane == 0) qny[rbase + j] = s;
            }
        }
    }
    grid.sync();

    // ========== P6: epilogue with local 34x34 LDL, 512 tasks ==========
    for (int tau = b; tau < 512; tau += G) {
        int qt = tau >> 5, c = tau & 31;
        float* Ml = smA;            // 34 x stride 35
        float* wL = smB;            // 34 x stride 68
        float* sDi = sX;            // 34
        float* gsm = sX + 40;       // 34
        int*   sidx = (int*)(sX + 80); // 32
        float kN = cons[CO_KN + c], kap = cons[CO_KAPPA];
        if (t < 32) sidx[t] = cidx[c * Nk + t];
        for (int e = t; e < 34 * 34; e += 256) {
            int i = e / 34, j = e - i * 34;
            Ml[i * 35 + j] = Mbuf[c * 1224 + i * 36 + j];
        }
        __syncthreads();
        if (t < 34) {
            gsm[t] = Ml[t * 35 + 32];     // raw gram col 32 (incl. gmm at t=32)
            float add = (t < 32) ? 1.f : ((t == 32) ? (-1.f / kN) : (1.f / kap));
            Ml[t * 35 + t] += add;
        }
        __syncthreads();
        // LDL (C-form): one sync per step
        for (int j = 0; j < 34; ++j) {
            if (t >= j && t < 34) {
                float s = Ml[t * 35 + j];
                for (int k = 0; k < j; ++k) s -= Ml[t * 35 + k] * Ml[j * 35 + k] * sDi[k];
                Ml[t * 35 + j] = s;
                if (t == j) sDi[j] = 1.f / s;
            }
            __syncthreads();
        }
        if (t == 0) {
            float ld = 0.f;
            for (int j = 0; j < 34; ++j) ld += logf(fabsf(Ml[j * 35 + j]));
            float scale = cons[CO_SCALE + c];
            float logdet = (float)Dk * logf(scale) + extraf[0] + logf(kN) + logf(kap) + ld;
            sX[116] = cons[CO_BIASA + c] - 0.5f * logdet;
        }
        // build w
        for (int e = t; e < 34 * NB; e += 256) {
            int i = e >> 6, qq = e & 63;
            int prow = (i < 32) ? sidx[i] : ((i == 32) ? (Nk + c) : (Nk + Ck));
            wL[i * 68 + qq] = P[(size_t)prow * Qk + qt * NB + qq] - gsm[i];
        }
        __syncthreads();
        if (t < 64) {
            int q = t;
            float w32 = wL[32 * 68 + q];
            float quad = 0.f;
#pragma unroll 1
            for (int i = 0; i < 34; ++i) {
                float s = wL[i * 68 + q];
                for (int k = 0; k < i; ++k) s -= Ml[i * 35 + k] * wL[k * 68 + q];
                float ti = s * sDi[i];
                wL[i * 68 + q] = ti;
                quad += s * ti;
            }
            int qg = qt * NB + q;
            float gmmv = gsm[32];
            float ydist2 = qny[qg] - 2.f * w32 - gmmv;
            float dd = qno[qg] + mun2o[c] - 2.f * QM[(size_t)c * Qk + qg];
            float scale = cons[CO_SCALE + c], common = cons[CO_COMMON + c];
            float dist = (1.f - REGP) / scale * (ydist2 - quad) + REGP * dd;
            out[(size_t)qg * Ck + c] = sX[116] - cons[CO_COEF + c] * log1pf(dist / common);
        }
        __syncthreads();
    }
}

extern "C" void kernel_launch(void* const* d_in, const int* in_sizes, int n_in,
                              void* d_out, int out_size, void* d_ws, size_t ws_size,
                              hipStream_t stream) {
    const float* sx = (const float*)d_in[0];
    const float* qx = (const float*)d_in[1];
    const int* labels = (const int*)d_in[2];
    const float* mvec = (const float*)d_in[3];
    const float* kappa = (const float*)d_in[4];
    const float* nu = (const float*)d_in[5];
    const float* td = (const float*)d_in[6];
    const float* tl = (const float*)d_in[7];
    float* W = (float*)d_ws;
    float* out = (float*)d_out;

    int nb = 1;
    hipOccupancyMaxActiveBlocksPerMultiprocessor(&nb, (const void*)k_all, 256, 0);
    if (nb < 1) nb = 1;
    if (nb > 4) nb = 4;
    int grid = nb * 256;

    void* args[] = {&sx, &qx, &labels, &mvec, &kappa, &nu, &td, &tl, &W, &out};
    hipLaunchCooperativeKernel((const void*)k_all, dim3(grid), dim3(256), args, 0, stream);
}

// Round 9
// 937.566 us; speedup vs baseline: 1.2547x; 1.2547x over previous
//
#include <hip/hip_runtime.h>
#include <hip/hip_cooperative_groups.h>
#include <math.h>

namespace cg = cooperative_groups;

#define Dk 1024
#define Ck 32
#define Nk 1024
#define Qk 1024
#define REGP 0.5f
#define NB 64
#define NT (Dk/NB)
#define NROWSV (Qk + Nk + Ck + 1)   // 2081 rows: queries, support (original order), mus, m

// consts layout (floats)
#define CO_KAPPA 0
#define CO_NU    1
#define CO_NJ    2
#define CO_KN    34
#define CO_SCALE 66
#define CO_COMMON 98
#define CO_COEF  130
#define CO_BIASA 162
#define CO_TOTAL 256

// workspace offsets (floats)
#define O_Y    ((size_t)0)
#define O_YO   (O_Y + 2112u*1024u)
#define O_W    (O_YO + 2112u*1024u)
#define O_T    (O_W + 1024u*1024u)
#define O_P    (O_T + 512u*512u)
#define O_MU   (O_P + 1088u*1024u)
#define O_QM   (O_MU + 32u*1024u)
#define O_MB   (O_QM + 32u*1024u)
#define O_QNY  (O_MB + 32u*1224u)
#define O_QNO  (O_QNY + 1024u)
#define O_MUN  (O_QNO + 1024u)
#define O_EX   (O_MUN + 32u)
#define O_CONS (O_EX + 16u)
#define O_CIDX (O_CONS + 256u)

__device__ __forceinline__ float wave_red(float s) {
#pragma unroll
    for (int o = 32; o > 0; o >>= 1) s += __shfl_down(s, o, 64);
    return s;
}

// thread owns a 4x4 sub-tile: rows rg*4..+3, cols c4*4..+3
__device__ __forceinline__ void fetch4(float4* reg, const float* src, int ld,
                                       int rowbase, int rowmax, int colbase, int t) {
    int rg = t >> 4, c4 = t & 15;
#pragma unroll
    for (int u = 0; u < 4; ++u) {
        int gr = rowbase + rg * 4 + u;
        reg[u] = (gr < rowmax) ? *(const float4*)(src + (size_t)gr * ld + colbase + c4 * 4)
                               : make_float4(0.f, 0.f, 0.f, 0.f);
    }
}
// transposed store via in-register 4x4 transpose: dst[k*68 + r], float4 writes
__device__ __forceinline__ void stT(float* dst, const float4* reg, int t) {
    int rg = t >> 4, c4 = t & 15;
    float4 v0 = make_float4(reg[0].x, reg[1].x, reg[2].x, reg[3].x);
    float4 v1 = make_float4(reg[0].y, reg[1].y, reg[2].y, reg[3].y);
    float4 v2 = make_float4(reg[0].z, reg[1].z, reg[2].z, reg[3].z);
    float4 v3 = make_float4(reg[0].w, reg[1].w, reg[2].w, reg[3].w);
    *(float4*)(dst + (c4 * 4 + 0) * 68 + rg * 4) = v0;
    *(float4*)(dst + (c4 * 4 + 1) * 68 + rg * 4) = v1;
    *(float4*)(dst + (c4 * 4 + 2) * 68 + rg * 4) = v2;
    *(float4*)(dst + (c4 * 4 + 3) * 68 + rg * 4) = v3;
}
// straight store: dst[r*68 + c]
__device__ __forceinline__ void stN(float* dst, const float4* reg, int t) {
    int rg = t >> 4, c4 = t & 15;
#pragma unroll
    for (int u = 0; u < 4; ++u)
        *(float4*)(dst + (rg * 4 + u) * 68 + c4 * 4) = reg[u];
}

// acc[r][s] += sum_k At[k][ty*4+r] * Bt[k][tx*4+s]
__device__ __forceinline__ void gemm16(const float* At, const float* Bt,
                                       float acc[4][4], int tx, int ty) {
#pragma unroll 4
    for (int kk = 0; kk < NB; ++kk) {
        float4 a = *(const float4*)(At + kk * 68 + ty * 4);
        float4 b = *(const float4*)(Bt + kk * 68 + tx * 4);
        float av[4] = {a.x, a.y, a.z, a.w};
        float bv[4] = {b.x, b.y, b.z, b.w};
#pragma unroll
        for (int r = 0; r < 4; ++r)
#pragma unroll
            for (int s = 0; s < 4; ++s) acc[r][s] += av[r] * bv[s];
    }
}

// register double-buffered k-loop tile GEMM
__device__ __forceinline__ void mm_task(
    const float* aSrc, int aLd, int aRow, int aRowMax, int aCol, int aRowStep, int aColStep,
    const float* bSrc, int bLd, int bRow, int bRowMax, int bCol, int bRowStep, int bColStep,
    bool bTrans, int k0, int k1,
    float acc[4][4], float* smA, float* smB, int t, int tx, int ty)
{
    float4 ra[4], rb[4];
    fetch4(ra, aSrc, aLd, aRow + k0 * aRowStep, aRowMax, aCol + k0 * aColStep, t);
    fetch4(rb, bSrc, bLd, bRow + k0 * bRowStep, bRowMax, bCol + k0 * bColStep, t);
    stT(smA, ra, t);
    if (bTrans) stT(smB, rb, t); else stN(smB, rb, t);
    __syncthreads();
    for (int kt = k0; kt < k1; ++kt) {
        if (kt + 1 < k1) {
            fetch4(ra, aSrc, aLd, aRow + (kt + 1) * aRowStep, aRowMax, aCol + (kt + 1) * aColStep, t);
            fetch4(rb, bSrc, bLd, bRow + (kt + 1) * bRowStep, bRowMax, bCol + (kt + 1) * bColStep, t);
        }
        gemm16(smA, smB, acc, tx, ty);
        __syncthreads();
        if (kt + 1 < k1) {
            stT(smA, ra, t);
            if (bTrans) stT(smB, rb, t); else stN(smB, rb, t);
        }
        __syncthreads();
    }
}

// LDS-resident 64x64 lower-tri inversion: column j per thread (t<64),
// smOut[i*68+j] = inv[i][j]. Proven in r5-r7 (keeps VGPR bounded).
__device__ __forceinline__ void tri_inv64(const float* smIn, float* smOut, int t) {
    if (t < NB) {
        int j = t;
        for (int i = 0; i < j; ++i) smOut[i * 68 + j] = 0.f;
        smOut[j * 68 + j] = 1.f / smIn[j * 68 + j];
        for (int i = j + 1; i < NB; ++i) {
            float s = 0.f;
            for (int k = j; k < i; ++k) s += smIn[i * 68 + k] * smOut[k * 68 + j];
            smOut[i * 68 + j] = -s / smIn[i * 68 + i];
        }
    }
}

__global__ __launch_bounds__(256) void k_all(const float* sx, const float* qx,
                                             const int* labels, const float* mvec,
                                             const float* kappa, const float* nu,
                                             const float* td, const float* tl,
                                             float* Wbuf, float* out) {
    cg::grid_group grid = cg::this_grid();
    __shared__ __align__(16) float smem[8832];
    float* smA = smem;            // 4352
    float* smB = smem + 4352;     // 4352
    float* sX  = smem + 8704;     // 128

    float* Y     = Wbuf + O_Y;
    float* Yo    = Wbuf + O_YO;
    float* W     = Wbuf + O_W;
    float* Tb    = Wbuf + O_T;
    float* P     = Wbuf + O_P;
    float* mu    = Wbuf + O_MU;
    float* QM    = Wbuf + O_QM;
    float* Mbuf  = Wbuf + O_MB;
    float* qny   = Wbuf + O_QNY;
    float* qno   = Wbuf + O_QNO;
    float* mun2o = Wbuf + O_MUN;
    float* extraf= Wbuf + O_EX;
    float* cons  = Wbuf + O_CONS;
    int*   cidx  = (int*)(Wbuf + O_CIDX);

    const int b = blockIdx.x, G = gridDim.x;
    const int t = threadIdx.x;
    const int tx = t & 15, ty = t >> 4;
    const int lane = t & 63, wv = t >> 6;
    const int BIG = 1 << 30;

    // ===== S0: stats, logdet, l1-full (diag-inv + 128-merge), zeros, qno, copies =====
    for (int tau = b; tau < 521; tau += G) {
        if (tau == 0) {
            int* scnt = (int*)sX;
            if (t < Ck) scnt[t] = 0;
            __syncthreads();
            for (int n = t; n < Nk; n += 256) {
                int l = labels[n];
                int pos = atomicAdd(&scnt[l], 1);
                cidx[l * Nk + pos] = n;
            }
            __syncthreads();
            if (t < Ck) {
                float kap = fabsf(kappa[0]) + 1e-6f;
                float nu_ = fmaxf(nu[0], (float)(Dk - 1) + 1e-6f);
                float Njf = (float)scnt[t];
                float kN = kap + Njf;
                if (t == 0) { cons[CO_KAPPA] = kap; cons[CO_NU] = nu_; }
                cons[CO_NJ + t] = Njf;
                cons[CO_KN + t] = kN;
                cons[CO_SCALE + t] = (kN + 1.0f) / ((nu_ + Njf - (float)Dk + 1.0f) * kN);
                float common = nu_ + Njf + 1.0f - (float)Dk;
                cons[CO_COMMON + t] = common;
                cons[CO_COEF + t] = 0.5f * (common + (float)Dk);
                cons[CO_BIASA + t] = lgammaf(0.5f * (common + (float)Dk)) - lgammaf(0.5f * common)
                                     - 0.5f * (float)Dk * logf(common);
            }
            __syncthreads();
        } else if (tau == 1) {
            float s = 0.f;
            for (int i = t; i < Dk; i += 256) s += logf(fabsf(td[i]));
            s = wave_red(s);
            if (lane == 0) sX[wv] = s;
            __syncthreads();
            if (t == 0) extraf[0] = 2.f * (sX[0] + sX[1] + sX[2] + sX[3]);
            __syncthreads();
        } else if (tau < 10) {
            // l1-full for pair p: invert C diag, invert A diag, merge X = -Cinv*(B*Ainv).
            int p = tau - 2, pb = p * 128;
            // (a) Cinv
            for (int idx = t; idx < NB * NB; idx += 256) {
                int r = idx >> 6, c = idx & 63;
                smA[r * 68 + c] = (c < r) ? tl[(size_t)(pb + 64 + r) * Dk + pb + 64 + c]
                                          : ((c == r) ? fabsf(td[pb + 64 + r]) : 0.f);
            }
            __syncthreads();
            tri_inv64(smA, smB, t);
            __syncthreads();
            for (int idx = t; idx < NB * NB; idx += 256) {
                int r = idx >> 6, c = idx & 63;
                W[(size_t)(pb + 64 + r) * Dk + pb + 64 + c] = smB[r * 68 + c];
            }
            // (b) Ainv
            for (int idx = t; idx < NB * NB; idx += 256) {
                int r = idx >> 6, c = idx & 63;
                smA[r * 68 + c] = (c < r) ? tl[(size_t)(pb + r) * Dk + pb + c]
                                          : ((c == r) ? fabsf(td[pb + r]) : 0.f);
            }
            __syncthreads();
            tri_inv64(smA, smB, t);
            __syncthreads();
            for (int idx = t; idx < NB * NB; idx += 256) {
                int r = idx >> 6, c = idx & 63;
                W[(size_t)(pb + r) * Dk + pb + c] = smB[r * 68 + c];
            }
            // (c) T = B * Ainv  (smA <- B transposed; smB holds Ainv straight)
            {
                float4 rb4[4];
                fetch4(rb4, tl, Dk, pb + 64, BIG, pb, t);
                stT(smA, rb4, t);
            }
            __syncthreads();
            float accT[4][4] = {};
            gemm16(smA, smB, accT, tx, ty);
            __syncthreads();
            // (d) smA <- T straight; smB <- Cinv transposed (reload from W)
#pragma unroll
            for (int r = 0; r < 4; ++r)
#pragma unroll
                for (int s = 0; s < 4; ++s)
                    smA[(ty * 4 + r) * 68 + tx * 4 + s] = accT[r][s];
            {
                float4 rc4[4];
                fetch4(rc4, W, Dk, pb + 64, BIG, pb + 64, t);
                stT(smB, rc4, t);
            }
            __syncthreads();
            float accX[4][4] = {};
            gemm16(smB, smA, accX, tx, ty);
#pragma unroll
            for (int r = 0; r < 4; ++r)
#pragma unroll
                for (int s = 0; s < 4; ++s)
                    W[(size_t)(pb + 64 + ty * 4 + r) * Dk + pb + tx * 4 + s] = -accX[r][s];
            __syncthreads();
            // (e) zero upper-right 64-block of pair
            for (int idx = t; idx < NB * 16; idx += 256) {
                int r = idx >> 4, c4 = idx & 15;
                ((float4*)(W + (size_t)(pb + r) * Dk + pb + 64))[c4] = make_float4(0, 0, 0, 0);
            }
        } else if (tau < 122) {        // zero strictly-upper W tiles not in same 128-pair
            int e = tau - 10;
            int ti = 0;
            while (true) { int cnt = ((ti & 1) ? 15 : 14) - ti; if (e < cnt) break; e -= cnt; ++ti; }
            int tj = ((ti & 1) ? (ti + 1) : (ti + 2)) + e;
            for (int idx = t; idx < NB * 16; idx += 256) {
                int r = idx >> 4, c4 = idx & 15;
                ((float4*)(W + (size_t)(ti * NB + r) * Dk + tj * NB))[c4] = make_float4(0, 0, 0, 0);
            }
        } else if (tau < 254) {        // zero Yo (2112 rows)
            int rbase = (tau - 122) * 16;
            for (int j = 0; j < 16; ++j)
                ((float4*)(Yo + (size_t)(rbase + j) * Dk))[t] = make_float4(0, 0, 0, 0);
        } else if (tau < 322) {        // zero P (1088 rows)
            int rbase = (tau - 254) * 16;
            for (int j = 0; j < 16; ++j)
                ((float4*)(P + (size_t)(rbase + j) * Qk))[t] = make_float4(0, 0, 0, 0);
        } else if (tau < 324) {        // zero QM
            int base = (tau - 322) * 16384;
#pragma unroll
            for (int j = 0; j < 4; ++j)
                ((float4*)(QM + base + j * 4096))[t] = make_float4(0, 0, 0, 0);
        } else if (tau < 327) {        // zero Mbuf (39168)
            int base = (tau - 324) * 13056;
            for (int i = t; i < 13056; i += 256) Mbuf[base + i] = 0.f;
        } else if (tau == 327) {
            if (t < 32) mun2o[t] = 0.f;
        } else if (tau < 392) {        // qno
            int rbase = (tau - 328) * 16;
            for (int j = wv; j < 16; j += 4) {
                const float* row = qx + (size_t)(rbase + j) * Dk;
                float s = 0.f;
                for (int d = lane; d < Dk; d += 64) { float v = row[d]; s += v * v; }
                s = wave_red(s);
                if (lane == 0) qno[rbase + j] = s;
            }
        } else if (tau < 456) {        // copy queries into Y
            int rbase = (tau - 392) * 16;
            for (int j = 0; j < 16; ++j) {
                int r = rbase + j;
                ((float4*)(Y + (size_t)r * Dk))[t] = ((const float4*)(qx + (size_t)r * Dk))[t];
            }
        } else if (tau < 520) {        // copy support (original order) into Y
            int rbase = (tau - 456) * 16;
            for (int j = 0; j < 16; ++j) {
                int n = rbase + j;
                ((float4*)(Y + (size_t)(Qk + n) * Dk))[t] = ((const float4*)(sx + (size_t)n * Dk))[t];
            }
        } else {                       // m row
            ((float4*)(Y + (size_t)(Qk + Nk + Ck) * Dk))[t] = ((const float4*)mvec)[t];
        }
    }
    grid.sync();

    // ===== S1: mu (128) + l2A (16) =====
    for (int tau = b; tau < 144; tau += G) {
        if (tau < 128) {
            int c = tau >> 2;
            int d = ((tau & 3) << 8) + t;
            int* sidx = (int*)(sX + 64);
            if (t < 32) sidx[t] = cidx[c * Nk + t];
            __syncthreads();
            int Nj = (int)cons[CO_NJ + c];
            float kap = cons[CO_KAPPA], kN = cons[CO_KN + c];
            float a0 = 0.f, a1 = 0.f, a2 = 0.f, a3 = 0.f;
            int lim = Nj < 32 ? Nj : 32;
            int s = 0;
            for (; s + 3 < lim; s += 4) {
                a0 += sx[(size_t)sidx[s] * Dk + d];
                a1 += sx[(size_t)sidx[s + 1] * Dk + d];
                a2 += sx[(size_t)sidx[s + 2] * Dk + d];
                a3 += sx[(size_t)sidx[s + 3] * Dk + d];
            }
            for (; s < lim; ++s) a0 += sx[(size_t)sidx[s] * Dk + d];
            for (; s < Nj; ++s) a0 += sx[(size_t)cidx[c * Nk + s] * Dk + d];
            float muv = (kap * mvec[d] + ((a0 + a1) + (a2 + a3))) / kN;
            mu[c * Dk + d] = muv;
            Y[(size_t)(Qk + Nk + c) * Dk + d] = muv;
            float s2 = wave_red(muv * muv);
            if (lane == 0) sX[wv] = s2;
            __syncthreads();
            if (t == 0) atomicAdd(&mun2o[c], sX[0] + sX[1] + sX[2] + sX[3]);
            __syncthreads();
        } else {
            int e = tau - 128;           // l2A: h=128, ht=2, pairs=4
            int p = e >> 2, rr = e & 3, i = rr >> 1, j = rr & 1;
            int h = 128, ht = 2, pb = p * 256;
            float acc[4][4] = {};
            mm_task(tl, Dk, pb + h + i * NB, BIG, pb, 0, NB,
                    W, Dk, pb, BIG, pb + j * NB, NB, 0, false, 0, ht,
                    acc, smA, smB, t, tx, ty);
            float* Tp = Tb + (size_t)p * h * h;
#pragma unroll
            for (int r = 0; r < 4; ++r)
#pragma unroll
                for (int s = 0; s < 4; ++s)
                    Tp[(size_t)(i * NB + ty * 4 + r) * h + j * NB + tx * 4 + s] = acc[r][s];
        }
    }
    grid.sync();

    // ===== S2: l2B (16) + QM split-K (64) =====
    for (int tau = b; tau < 80; tau += G) {
        if (tau < 16) {
            int p = tau >> 2, rr = tau & 3, i = rr >> 1, j = rr & 1;
            int h = 128, ht = 2, pb = p * 256;
            const float* Tp = Tb + (size_t)p * h * h;
            float acc[4][4] = {};
            mm_task(W, Dk, pb + h + i * NB, BIG, pb + h, 0, NB,
                    Tp, h, 0, BIG, j * NB, NB, 0, false, 0, ht,
                    acc, smA, smB, t, tx, ty);
#pragma unroll
            for (int r = 0; r < 4; ++r)
#pragma unroll
                for (int s = 0; s < 4; ++s)
                    W[(size_t)(pb + h + i * NB + ty * 4 + r) * Dk + pb + j * NB + tx * 4 + s] = -acc[r][s];
        } else {
            int e = tau - 16;
            int qt = e >> 2, kc = e & 3;
            float acc[4][4] = {};
            mm_task(mu, Dk, 0, Ck, 0, 0, NB,
                    qx, Dk, qt * NB, Qk, 0, 0, NB, true, kc * 4, kc * 4 + 4,
                    acc, smA, smB, t, tx, ty);
#pragma unroll
            for (int r = 0; r < 4; ++r) {
                int c = ty * 4 + r;
                if (c < Ck)
#pragma unroll
                    for (int s = 0; s < 4; ++s)
                        atomicAdd(&QM[(size_t)c * Qk + qt * NB + tx * 4 + s], acc[r][s]);
            }
        }
    }
    grid.sync();

    // ===== S3/S4: trtri level 3 (h=256) =====
    {
        int h = 256, ht = 4;
        for (int tau = b; tau < 2 * ht * ht; tau += G) {
            int p = tau / (ht * ht), rr = tau % (ht * ht);
            int i = rr / ht, j = rr % ht;
            int pb = p * 2 * h;
            float acc[4][4] = {};
            mm_task(tl, Dk, pb + h + i * NB, BIG, pb, 0, NB,
                    W, Dk, pb, BIG, pb + j * NB, NB, 0, false, 0, ht,
                    acc, smA, smB, t, tx, ty);
            float* Tp = Tb + (size_t)p * h * h;
#pragma unroll
            for (int r = 0; r < 4; ++r)
#pragma unroll
                for (int s = 0; s < 4; ++s)
                    Tp[(size_t)(i * NB + ty * 4 + r) * h + j * NB + tx * 4 + s] = acc[r][s];
        }
        grid.sync();
        for (int tau = b; tau < 2 * ht * ht; tau += G) {
            int p = tau / (ht * ht), rr = tau % (ht * ht);
            int i = rr / ht, j = rr % ht;
            int pb = p * 2 * h;
            const float* Tp = Tb + (size_t)p * h * h;
            float acc[4][4] = {};
            mm_task(W, Dk, pb + h + i * NB, BIG, pb + h, 0, NB,
                    Tp, h, 0, BIG, j * NB, NB, 0, false, 0, ht,
                    acc, smA, smB, t, tx, ty);
#pragma unroll
            for (int r = 0; r < 4; ++r)
#pragma unroll
                for (int s = 0; s < 4; ++s)
                    W[(size_t)(pb + h + i * NB + ty * 4 + r) * Dk + pb + j * NB + tx * 4 + s] = -acc[r][s];
        }
        grid.sync();
    }

    // ===== S5: l4A (64 tasks, h=512) + Ygemm-left (jt 0..7, 396 tasks) =====
    for (int tau = b; tau < 460; tau += G) {
        if (tau < 64) {
            int ht = 8, i = tau / ht, j = tau % ht;
            float acc[4][4] = {};
            mm_task(tl, Dk, 512 + i * NB, BIG, 0, 0, NB,
                    W, Dk, 0, BIG, j * NB, NB, 0, false, 0, ht,
                    acc, smA, smB, t, tx, ty);
#pragma unroll
            for (int r = 0; r < 4; ++r)
#pragma unroll
                for (int s = 0; s < 4; ++s)
                    Tb[(size_t)(i * NB + ty * 4 + r) * 512 + j * NB + tx * 4 + s] = acc[r][s];
        } else {
            int e = tau - 64;
            int rt = e / 12, w = e % 12;
            int jt, kc;
            if (w < 4) { jt = w; kc = 0; }
            else { jt = 4 + ((w - 4) >> 1); kc = (w - 4) & 1; }
            int k0 = kc * 4, k1 = min(jt + 1, k0 + 4);
            float acc[4][4] = {};
            mm_task(Y, Dk, rt * NB, NROWSV, 0, 0, NB,
                    W, Dk, jt * NB, BIG, 0, 0, NB, true, k0, k1,
                    acc, smA, smB, t, tx, ty);
#pragma unroll
            for (int r = 0; r < 4; ++r) {
                int gr = rt * NB + ty * 4 + r;
                if (gr < NROWSV)
#pragma unroll
                    for (int s = 0; s < 4; ++s)
                        atomicAdd(&Yo[(size_t)gr * Dk + jt * NB + tx * 4 + s], acc[r][s]);
            }
        }
    }
    grid.sync();

    // ===== S6: l4B (64) =====
    for (int tau = b; tau < 64; tau += G) {
        int ht = 8, i = tau / ht, j = tau % ht;
        float acc[4][4] = {};
        mm_task(W, Dk, 512 + i * NB, BIG, 512, 0, NB,
                Tb, 512, 0, BIG, j * NB, NB, 0, false, 0, ht,
                acc, smA, smB, t, tx, ty);
#pragma unroll
        for (int r = 0; r < 4; ++r)
#pragma unroll
            for (int s = 0; s < 4; ++s)
                W[(size_t)(512 + i * NB + ty * 4 + r) * Dk + j * NB + tx * 4 + s] = -acc[r][s];
    }
    grid.sync();

    // ===== S7: Ygemm-right (jt 8..15, 924 tasks) =====
    for (int e = b; e < 33 * 28; e += G) {
        int rt = e / 28, w = e % 28;
        int jt, kc;
        if (w < 12) { jt = 8 + w / 3; kc = w % 3; }
        else { jt = 12 + (w - 12) / 4; kc = (w - 12) % 4; }
        int k0 = kc * 4, k1 = min(jt + 1, k0 + 4);
        float acc[4][4] = {};
        mm_task(Y, Dk, rt * NB, NROWSV, 0, 0, NB,
                W, Dk, jt * NB, BIG, 0, 0, NB, true, k0, k1,
                acc, smA, smB, t, tx, ty);
#pragma unroll
        for (int r = 0; r < 4; ++r) {
            int gr = rt * NB + ty * 4 + r;
            if (gr < NROWSV)
#pragma unroll
                for (int s = 0; s < 4; ++s)
                    atomicAdd(&Yo[(size_t)gr * Dk + jt * NB + tx * 4 + s], acc[r][s]);
        }
    }
    grid.sync();

    // ===== S8: P split-K (1088), gram split-K (128), qny (64) =====
    for (int tau = b; tau < 1280; tau += G) {
        if (tau < 1088) {
            int kc = tau & 3, qt = (tau >> 2) & 15, nt = tau >> 6;
            float acc[4][4] = {};
            mm_task(Yo + (size_t)Qk * Dk, Dk, nt * NB, Nk + Ck + 1, 0, 0, NB,
                    Yo, Dk, qt * NB, Qk, 0, 0, NB, true, kc * 4, kc * 4 + 4,
                    acc, smA, smB, t, tx, ty);
#pragma unroll
            for (int r = 0; r < 4; ++r) {
                int n = nt * NB + ty * 4 + r;
                if (n < Nk + Ck + 1)
#pragma unroll
                    for (int s = 0; s < 4; ++s)
                        atomicAdd(&P[(size_t)n * Qk + qt * NB + tx * 4 + s], acc[r][s]);
            }
        } else if (tau < 1216) {
            int g = tau - 1088;
            int c = g >> 2, kc = g & 3;
            int* sidx = (int*)sX;
            if (t < 32) sidx[t] = cidx[c * Nk + t];
            __syncthreads();
            float accg[5];
            int iu[5], ju[5];
#pragma unroll
            for (int u = 0; u < 5; ++u) {
                int e = t + u * 256;
                iu[u] = e / 34; ju[u] = e - iu[u] * 34;
                accg[u] = 0.f;
            }
            for (int kt = kc * 4; kt < kc * 4 + 4; ++kt) {
                for (int e2 = t; e2 < 34 * NB; e2 += 256) {
                    int i = e2 >> 6, k = e2 & 63;
                    int yr = (i < 32) ? (Qk + sidx[i]) : ((i == 32) ? (Qk + Nk + c) : (Qk + Nk + Ck));
                    smA[i * 68 + k] = Yo[(size_t)yr * Dk + kt * NB + k];
                }
                __syncthreads();
#pragma unroll
                for (int u = 0; u < 5; ++u) {
                    int e = t + u * 256;
                    if (e < 1156) {
                        float s = 0.f;
                        for (int k = 0; k < NB; ++k) s += smA[iu[u] * 68 + k] * smA[ju[u] * 68 + k];
                        accg[u] += s;
                    }
                }
                __syncthreads();
            }
#pragma unroll
            for (int u = 0; u < 5; ++u) {
                int e = t + u * 256;
                if (e < 1156)
                    atomicAdd(&Mbuf[c * 1224 + iu[u] * 36 + ju[u]], accg[u]);
            }
            __syncthreads();
        } else {
            int rbase = (tau - 1216) * 16;
            for (int j = wv; j < 16; j += 4) {
                const float* row = Yo + (size_t)(rbase + j) * Dk;
                float s = 0.f;
                for (int d = lane; d < Dk; d += 64) { float v = row[d]; s += v * v; }
                s = wave_red(s);
                if (lane == 0) qny[rbase + j] = s;
            }
        }
    }
    grid.sync();

    // ===== S9: epilogue with local 34x34 LDL, 512 tasks =====
    for (int tau = b; tau < 512; tau += G) {
        int qt = tau >> 5, c = tau & 31;
        float* Ml = smA;            // 34 x stride 35
        float* wL = smB;            // 34 x stride 68
        float* sDi = sX;            // 34
        float* gsm = sX + 40;       // 34
        int*   sidx = (int*)(sX + 80); // 32
        float kN = cons[CO_KN + c], kap = cons[CO_KAPPA];
        if (t < 32) sidx[t] = cidx[c * Nk + t];
        for (int e = t; e < 34 * 34; e += 256) {
            int i = e / 34, j = e - i * 34;
            Ml[i * 35 + j] = Mbuf[c * 1224 + i * 36 + j];
        }
        __syncthreads();
        if (t < 34) {
            gsm[t] = Ml[t * 35 + 32];     // raw gram col 32 (incl. gmm at t=32)
            float add = (t < 32) ? 1.f : ((t == 32) ? (-1.f / kN) : (1.f / kap));
            Ml[t * 35 + t] += add;
        }
        __syncthreads();
        for (int j = 0; j < 34; ++j) {
            if (t >= j && t < 34) {
                float s = Ml[t * 35 + j];
                for (int k = 0; k < j; ++k) s -= Ml[t * 35 + k] * Ml[j * 35 + k] * sDi[k];
                Ml[t * 35 + j] = s;
                if (t == j) sDi[j] = 1.f / s;
            }
            __syncthreads();
        }
        if (t == 0) {
            float ld = 0.f;
            for (int j = 0; j < 34; ++j) ld += logf(fabsf(Ml[j * 35 + j]));
            float scale = cons[CO_SCALE + c];
            float logdet = (float)Dk * logf(scale) + extraf[0] + logf(kN) + logf(kap) + ld;
            sX[116] = cons[CO_BIASA + c] - 0.5f * logdet;
        }
        for (int e = t; e < 34 * NB; e += 256) {
            int i = e >> 6, qq = e & 63;
            int prow = (i < 32) ? sidx[i] : ((i == 32) ? (Nk + c) : (Nk + Ck));
            wL[i * 68 + qq] = P[(size_t)prow * Qk + qt * NB + qq] - gsm[i];
        }
        __syncthreads();
        if (t < 64) {
            int q = t;
            float w32 = wL[32 * 68 + q];
            float quad = 0.f;
#pragma unroll 1
            for (int i = 0; i < 34; ++i) {
                float s = wL[i * 68 + q];
                for (int k = 0; k < i; ++k) s -= Ml[i * 35 + k] * wL[k * 68 + q];
                float ti = s * sDi[i];
                wL[i * 68 + q] = ti;
                quad += s * ti;
            }
            int qg = qt * NB + q;
            float gmmv = gsm[32];
            float ydist2 = qny[qg] - 2.f * w32 - gmmv;
            float dd = qno[qg] + mun2o[c] - 2.f * QM[(size_t)c * Qk + qg];
            float scale = cons[CO_SCALE + c], common = cons[CO_COMMON + c];
            float dist = (1.f - REGP) / scale * (ydist2 - quad) + REGP * dd;
            out[(size_t)qg * Ck + c] = sX[116] - cons[CO_COEF + c] * log1pf(dist / common);
        }
        __syncthreads();
    }
}

extern "C" void kernel_launch(void* const* d_in, const int* in_sizes, int n_in,
                              void* d_out, int out_size, void* d_ws, size_t ws_size,
                              hipStream_t stream) {
    const float* sx = (const float*)d_in[0];
    const float* qx = (const float*)d_in[1];
    const int* labels = (const int*)d_in[2];
    const float* mvec = (const float*)d_in[3];
    const float* kappa = (const float*)d_in[4];
    const float* nu = (const float*)d_in[5];
    const float* td = (const float*)d_in[6];
    const float* tl = (const float*)d_in[7];
    float* W = (float*)d_ws;
    float* out = (float*)d_out;

    // Clamp grid to guaranteed co-residency (cooperative launch errors out
    // silently if grid > capacity — r8 lesson). All phases are grid-stride,
    // so any grid size is correct.
    int nb = 1;
    hipOccupancyMaxActiveBlocksPerMultiprocessor(&nb, (const void*)k_all, 256, 0);
    if (nb < 1) nb = 1;
    int grid = nb * 256;
    if (grid > 512) grid = 512;

    void* args[] = {&sx, &qx, &labels, &mvec, &kappa, &nu, &td, &tl, &W, &out};
    hipLaunchCooperativeKernel((const void*)k_all, dim3(grid), dim3(256), args, 0, stream);
}